// Round 14
// baseline (172.859 us; speedup 1.0000x reference)
//
#include <hip/hip_runtime.h>
#include <hip/hip_bf16.h>
#include <stdint.h>

typedef unsigned short u16;
typedef unsigned int   u32;
typedef __attribute__((ext_vector_type(8))) __bf16 bf16x8;
typedef __attribute__((ext_vector_type(8))) _Float16 f16x8;
typedef __attribute__((ext_vector_type(2))) _Float16 f16x2;
typedef __attribute__((ext_vector_type(4))) float  f32x4;
typedef __attribute__((ext_vector_type(2))) u32    u32x2;
typedef __attribute__((ext_vector_type(4))) u32    u32x4;

#define B_  4
#define S_  1024
#define D_  1024
#define H_  16
#define AD_ 64

#if defined(__has_builtin)
#if __has_builtin(__builtin_amdgcn_cvt_pk_bf16_f32)
#define HAVE_CVT_PK 1
#endif
#if __has_builtin(__builtin_amdgcn_global_load_lds)
#define HAVE_GLL 1
#endif
#endif

#ifdef HAVE_CVT_PK
typedef __attribute__((ext_vector_type(2))) __bf16 bf16x2;
__device__ __forceinline__ u32 pack2(float a, float b) {
    bf16x2 r = __builtin_amdgcn_cvt_pk_bf16_f32(a, b);
    return __builtin_bit_cast(u32, r);
}
__device__ __forceinline__ u16 f2bf(float f) { return (u16)pack2(f, f); }
#else
__device__ __forceinline__ u16 f2bf(float f) {
    u32 u = __float_as_uint(f);
    u32 r = u + 0x7fffu + ((u >> 16) & 1u);   // RNE
    return (u16)(r >> 16);
}
__device__ __forceinline__ u32 pack2(float a, float b) {
    return (u32)f2bf(a) | ((u32)f2bf(b) << 16);
}
#endif

// pack two f32 into f16x2 (RTZ) as u32
__device__ __forceinline__ u32 pkf16(float a, float b) {
    return __builtin_bit_cast(u32, __builtin_amdgcn_cvt_pkrtz(a, b));
}
// t = relu(x)^2 for a pair, in packed f16 (cvt + pk_max + pk_mul)
__device__ __forceinline__ u32 relu2_f16(float a, float b) {
    f16x2 h = __builtin_bit_cast(f16x2, __builtin_amdgcn_cvt_pkrtz(a, b));
    f16x2 z = {(_Float16)0.f, (_Float16)0.f};
    h = __builtin_elementwise_max(h, z);
    h = h * h;
    return __builtin_bit_cast(u32, h);
}

// Async global->LDS, 16B/lane; dest = base + lane*16 (wave-uniform base).
// Source-side XOR swizzle preserves the LDS XOR fragment layout.
typedef __attribute__((address_space(1))) const u32 gas_u32;
typedef __attribute__((address_space(3))) u32 las_u32;
__device__ __forceinline__ void gll16(const void* g, void* l) {
#ifdef HAVE_GLL
    __builtin_amdgcn_global_load_lds((gas_u32*)g, (las_u32*)l, 16, 0, 0);
#else
    int lane = threadIdx.x & 63;
    *(uint4*)((u16*)l + lane * 8) = *(const uint4*)g;
#endif
}

// ---------------------------------------------------------------------------
// Kernel 0: fp32 -> bf16 pre-conversion of iQ, Wa, Wo (memory-bound).
// ---------------------------------------------------------------------------
__global__ __launch_bounds__(256) void conv_bf16(
    const float* __restrict__ a, const float* __restrict__ b,
    const float* __restrict__ c,
    u16* __restrict__ ao, u16* __restrict__ bo, u16* __restrict__ co,
    int na, int nb)
{
    int gid = blockIdx.x * 256 + threadIdx.x;
    int base = gid * 8;
    const float* src; u16* dst; int off;
    if (base < na)           { src = a; dst = ao; off = base; }
    else if (base < na + nb) { src = b; dst = bo; off = base - na; }
    else                     { src = c; dst = co; off = base - na - nb; }
    float4 v0 = *(const float4*)(src + off);
    float4 v1 = *(const float4*)(src + off + 4);
    u32 pk[4] = {pack2(v0.x, v0.y), pack2(v0.z, v0.w),
                 pack2(v1.x, v1.y), pack2(v1.z, v1.w)};
    *(uint4*)(dst + off) = *(uint4*)pk;
}

// ---------------------------------------------------------------------------
// Kernel 1: QKV = iQ @ Wa^T + ba  (M=4096, N=3072, K=1024), bf16 inputs.
// q (x0.125) bf16, k bf16, v transposed [B,H,64,S] f16.
// ---------------------------------------------------------------------------
__global__ __launch_bounds__(256, 3) void qkv_gemm(
    const u16* __restrict__ A, const u16* __restrict__ W,
    const float* __restrict__ bias,
    u16* __restrict__ qb, u16* __restrict__ kb, u16* __restrict__ vb)
{
    __shared__ u16 As[128 * 64];
    __shared__ u16 Bs[128 * 64];

    const int tid  = threadIdx.x;
    const int lane = tid & 63, w = tid >> 6;
    const int quad = lane >> 4, ln = lane & 15;
    const int wrow = (w >> 1) * 64, wcol = (w & 1) * 64;
    const int row0 = blockIdx.y * 128, col0 = blockIdx.x * 128;

    const int ri = lane >> 3, ci = lane & 7;
    const int scol = (ci ^ ri) << 3;

    f32x4 acc[4][4];
#pragma unroll
    for (int i = 0; i < 4; i++)
#pragma unroll
        for (int j = 0; j < 4; j++) acc[i][j] = (f32x4){0.f, 0.f, 0.f, 0.f};

    for (int kb_i = 0; kb_i < 16; ++kb_i) {
        const int k0 = kb_i * 64;
#pragma unroll
        for (int c = 0; c < 4; ++c) {
            int r0 = c * 32 + w * 8;
            int gr = r0 + ri;
            gll16(A + (size_t)(row0 + gr) * D_ + k0 + scol, &As[r0 * 64]);
            gll16(W + (size_t)(col0 + gr) * D_ + k0 + scol, &Bs[r0 * 64]);
        }
        __syncthreads();
#pragma unroll
        for (int ks = 0; ks < 2; ++ks) {
            bf16x8 af[4], bfr[4];
#pragma unroll
            for (int mt = 0; mt < 4; ++mt) {
                int r = wrow + mt * 16 + ln;
                af[mt] = *(bf16x8*)&As[r * 64 + (((ks * 4 + quad) ^ (r & 7)) << 3)];
            }
#pragma unroll
            for (int nt = 0; nt < 4; ++nt) {
                int r = wcol + nt * 16 + ln;
                bfr[nt] = *(bf16x8*)&Bs[r * 64 + (((ks * 4 + quad) ^ (r & 7)) << 3)];
            }
#pragma unroll
            for (int mt = 0; mt < 4; ++mt)
#pragma unroll
                for (int nt = 0; nt < 4; ++nt)
                    acc[mt][nt] = __builtin_amdgcn_mfma_f32_16x16x32_bf16(
                        af[mt], bfr[nt], acc[mt][nt], 0, 0, 0);
        }
        __syncthreads();
    }

    const int which = col0 >> 10;
#pragma unroll
    for (int mt = 0; mt < 4; ++mt) {
#pragma unroll
        for (int nt = 0; nt < 4; ++nt) {
            int n = col0 + wcol + nt * 16 + ln;
            float bv = bias[n];
            int h = (n >> 6) & 15, d = n & 63;
            if (which == 2) {
                int m0 = row0 + wrow + mt * 16 + quad * 4;
                int b = m0 >> 10, s0 = m0 & 1023;
                u32x2 pk;
                pk.x = pkf16(acc[mt][nt][0] + bv, acc[mt][nt][1] + bv);
                pk.y = pkf16(acc[mt][nt][2] + bv, acc[mt][nt][3] + bv);
                *(u32x2*)&vb[((size_t)((b * 16 + h) * 64 + d)) * 1024 + s0] = pk;
            } else {
#pragma unroll
                for (int reg = 0; reg < 4; ++reg) {
                    int m = row0 + wrow + mt * 16 + quad * 4 + reg;
                    int b = m >> 10, s = m & 1023;
                    float v = acc[mt][nt][reg] + bv;
                    if (which == 0)
                        qb[((size_t)((b * 16 + h) * 1024 + s)) * 64 + d] = f2bf(v * 0.125f);
                    else
                        kb[((size_t)((b * 16 + h) * 1024 + s)) * 64 + d] = f2bf(v);
                }
            }
        }
    }
}

// ---------------------------------------------------------------------------
// Kernel 2: fused attention — R11 structure with SINGLE-buffered K/V:
// LDS 64.5 -> 48.5KB => 3 blocks/CU (was 2). Cross-block overlap replaces
// in-block dbuf prefetch (m97-pattern: 2-barrier K-loop at 3 blocks/CU).
// f16 epilogue, far bias in MFMA C-init, Lsum via ones-MFMA.
// rel_s overlays k_s (rel read strictly before first K stage).
// ---------------------------------------------------------------------------
__global__ __launch_bounds__(256, 3) void attn_kernel(
    const u16* __restrict__ qb, const u16* __restrict__ kb,
    const u16* __restrict__ vb, const float* __restrict__ rel,
    const float* __restrict__ snb_p, u16* __restrict__ ctx)
{
    __shared__ u16 q_s[128 * 64];    // 16KB; t_s alias
    __shared__ u16 k_s[64 * 64];     // 8KB; rel_s alias (prologue only)
    __shared__ u16 v_s[64 * 64];     // 8KB
    __shared__ float qr[33 * 128];   // 16.5KB

    u16* t_s   = q_s;
    u16* rel_s = k_s;

    const int tid  = threadIdx.x;
    const int lane = tid & 63, w = tid >> 6;
    const int quad = lane >> 4, ln = lane & 15;
    const int bh = blockIdx.x >> 3, qt = blockIdx.x & 7;
    const int i0 = qt * 128;
    const float snb = snb_p[0];

    const u16* qplane = qb + ((size_t)bh * 1024 + i0) * 64;
    const u16* kplane = kb + (size_t)bh * 1024 * 64;
    const u16* vplane = vb + (size_t)bh * 64 * 1024;

    const int ri = lane >> 3, ci = lane & 7;
    const int scol = (ci ^ ri) << 3;

    const u32x4 ones_u = {0x3C003C00u, 0x3C003C00u, 0x3C003C00u, 0x3C003C00u};
    const f16x8 ones = __builtin_bit_cast(f16x8, ones_u);

#pragma unroll
    for (int c = 0; c < 4; ++c) {
        int r0 = w * 32 + c * 8;
        gll16(qplane + (size_t)(r0 + ri) * 64 + scol, &q_s[r0 * 64]);
    }
    for (int idx = tid; idx < 384; idx += 256) {
        int p = idx >> 3, c = idx & 7;
        u32 pk[4];
        if (p < 33) {
            const float* sp = rel + p * 64 + c * 8;
            float4 r0 = *(const float4*)sp;
            float4 r1 = *(const float4*)(sp + 4);
            pk[0] = pack2(r0.x, r0.y); pk[1] = pack2(r0.z, r0.w);
            pk[2] = pack2(r1.x, r1.y); pk[3] = pack2(r1.z, r1.w);
        } else { pk[0] = pk[1] = pk[2] = pk[3] = 0; }
        *(uint4*)&rel_s[p * 64 + ((c ^ (p & 7)) << 3)] = *(uint4*)pk;
    }
    __syncthreads();

    bf16x8 bq[2][2];   // [sub][ks]
#pragma unroll
    for (int sub = 0; sub < 2; ++sub) {
        int rq = w * 32 + sub * 16 + ln;
#pragma unroll
        for (int ks = 0; ks < 2; ++ks)
            bq[sub][ks] = *(bf16x8*)&q_s[rq * 64 + (((ks * 4 + quad) ^ (rq & 7)) << 3)];
    }

    // qr[p][i] = q[i]·rel[p] + snb  via MFMA  (reads rel_s = k_s overlay)
#pragma unroll
    for (int sub = 0; sub < 2; ++sub) {
        f32x4 qacc[3];
#pragma unroll
        for (int nt = 0; nt < 3; ++nt) qacc[nt] = (f32x4){0.f, 0.f, 0.f, 0.f};
#pragma unroll
        for (int ks = 0; ks < 2; ++ks) {
#pragma unroll
            for (int nt = 0; nt < 3; ++nt) {
                int rp = nt * 16 + ln;
                bf16x8 bp = *(bf16x8*)&rel_s[rp * 64 + (((ks * 4 + quad) ^ (rp & 7)) << 3)];
                qacc[nt] = __builtin_amdgcn_mfma_f32_16x16x32_bf16(bq[sub][ks], bp, qacc[nt], 0, 0, 0);
            }
        }
#pragma unroll
        for (int nt = 0; nt < 3; ++nt) {
            int p = nt * 16 + ln;
            if (p < 33) {
#pragma unroll
                for (int reg = 0; reg < 4; ++reg)
                    qr[p * 128 + w * 32 + sub * 16 + quad * 4 + reg] = qacc[nt][reg] + snb;
            }
        }
    }
    __syncthreads();   // qr visible; all rel_s reads complete (k_s reusable)

    float cL[2], cR[2];
#pragma unroll
    for (int sub = 0; sub < 2; ++sub) {
        int il = w * 32 + sub * 16 + ln;
        cL[sub] = qr[il];
        cR[sub] = qr[32 * 128 + il];
    }

    f32x4 o_acc[2][4], lacc[2];
#pragma unroll
    for (int sub = 0; sub < 2; ++sub) {
        lacc[sub] = (f32x4){0.f, 0.f, 0.f, 0.f};
#pragma unroll
        for (int nt = 0; nt < 4; ++nt) o_acc[sub][nt] = (f32x4){0.f, 0.f, 0.f, 0.f};
    }

    for (int jt = 0; jt < 16; ++jt) {
        const int j0 = jt * 64;
        // stage this tile (single buffer, m97-style 2-barrier loop)
#pragma unroll
        for (int c = 0; c < 2; ++c) {
            int r0 = w * 16 + c * 8;
            gll16(kplane + (size_t)(j0 + r0 + ri) * 64 + scol, &k_s[r0 * 64]);
            gll16(vplane + (size_t)(r0 + ri) * 1024 + j0 + scol, &v_s[r0 * 64]);
        }
        __syncthreads();   // staged data visible

        f32x4 sacc[2][4];
        bool faru[2][4];
#pragma unroll
        for (int sub = 0; sub < 2; ++sub) {
            const int ib = i0 + w * 32 + sub * 16;
#pragma unroll
            for (int mj = 0; mj < 4; ++mj) {
                const int diff = (j0 + mj * 16) - ib;
                faru[sub][mj] = (diff >= 32 || diff <= -32);
                float ci = faru[sub][mj] ? ((diff < 0) ? cL[sub] : cR[sub]) : 0.f;
                sacc[sub][mj] = (f32x4){ci, ci, ci, ci};
            }
        }
#pragma unroll
        for (int ks = 0; ks < 2; ++ks) {
#pragma unroll
            for (int mj = 0; mj < 4; ++mj) {
                int rk = mj * 16 + ln;
                bf16x8 ak = *(bf16x8*)&k_s[rk * 64 + (((ks * 4 + quad) ^ (rk & 7)) << 3)];
                sacc[0][mj] = __builtin_amdgcn_mfma_f32_16x16x32_bf16(ak, bq[0][ks], sacc[0][mj], 0, 0, 0);
                sacc[1][mj] = __builtin_amdgcn_mfma_f32_16x16x32_bf16(ak, bq[1][ks], sacc[1][mj], 0, 0, 0);
            }
        }

#pragma unroll
        for (int sub = 0; sub < 2; ++sub) {
            const int ib = i0 + w * 32 + sub * 16;
            const int row = w * 32 + sub * 16 + ln;
#pragma unroll
            for (int mj = 0; mj < 4; ++mj) {
                u32x2 pk;
                if (faru[sub][mj]) {
                    pk.x = relu2_f16(sacc[sub][mj][0], sacc[sub][mj][1]);
                    pk.y = relu2_f16(sacc[sub][mj][2], sacc[sub][mj][3]);
                } else {
                    const int jg0 = j0 + mj * 16;
                    float sv[4];
#pragma unroll
                    for (int reg = 0; reg < 4; ++reg) {
                        int dlt = jg0 + quad * 4 + reg - (ib + ln);
                        int p = min(max(dlt, -16), 16) + 16;
                        sv[reg] = sacc[sub][mj][reg] + qr[p * 128 + row];
                    }
                    pk.x = relu2_f16(sv[0], sv[1]);
                    pk.y = relu2_f16(sv[2], sv[3]);
                }
                int chunk = ((2 * mj + (quad >> 1)) ^ (row & 7));
                *(u32x2*)&t_s[row * 64 + (chunk << 3) + (quad & 1) * 4] = pk;
            }
        }

#pragma unroll
        for (int ks = 0; ks < 2; ++ks) {
            f16x8 at[2];
#pragma unroll
            for (int sub = 0; sub < 2; ++sub) {
                int rt = w * 32 + sub * 16 + ln;
                at[sub] = *(f16x8*)&t_s[rt * 64 + (((ks * 4 + quad) ^ (rt & 7)) << 3)];
            }
            lacc[0] = __builtin_amdgcn_mfma_f32_16x16x32_f16(at[0], ones, lacc[0], 0, 0, 0);
            lacc[1] = __builtin_amdgcn_mfma_f32_16x16x32_f16(at[1], ones, lacc[1], 0, 0, 0);
#pragma unroll
            for (int nt = 0; nt < 4; ++nt) {
                int rv = nt * 16 + ln;
                f16x8 bv = *(f16x8*)&v_s[rv * 64 + (((ks * 4 + quad) ^ (rv & 7)) << 3)];
                o_acc[0][nt] = __builtin_amdgcn_mfma_f32_16x16x32_f16(at[0], bv, o_acc[0][nt], 0, 0, 0);
                o_acc[1][nt] = __builtin_amdgcn_mfma_f32_16x16x32_f16(at[1], bv, o_acc[1][nt], 0, 0, 0);
            }
        }
        __syncthreads();   // all reads of k_s/v_s done before next stage
    }

    const int b = bh >> 4, h = bh & 15;
#pragma unroll
    for (int sub = 0; sub < 2; ++sub) {
#pragma unroll
        for (int reg = 0; reg < 4; ++reg) {
            int ig = i0 + w * 32 + sub * 16 + quad * 4 + reg;
            float li = 1.f / (lacc[sub][reg] + 1e-8f);
#pragma unroll
            for (int nt = 0; nt < 4; ++nt) {
                int dg = nt * 16 + ln;
                ctx[((size_t)(b * 1024 + ig)) * 1024 + h * 64 + dg] =
                    f2bf(o_acc[sub][nt][reg] * li);
            }
        }
    }
}

// ---------------------------------------------------------------------------
// Kernel 3: out = ctx @ Wo^T + bo  (M=4096, N=1024, K=1024), bf16 in, f32 out.
// 128x64 tiles, BK=128.
// ---------------------------------------------------------------------------
__global__ __launch_bounds__(256) void out_gemm(
    const u16* __restrict__ A, const u16* __restrict__ W,
    const float* __restrict__ bias, float* __restrict__ out)
{
    __shared__ u16 As[128 * 128];   // 32KB
    __shared__ u16 Bs[64 * 128];    // 16KB

    const int tid  = threadIdx.x;
    const int lane = tid & 63, w = tid >> 6;
    const int quad = lane >> 4, ln = lane & 15;
    const int wrow = (w >> 1) * 64, wcol = (w & 1) * 32;
    const int row0 = blockIdx.y * 128, col0 = blockIdx.x * 64;

    const int ri4  = lane >> 4;
    const int ci16 = lane & 15;

    f32x4 acc[4][2];
#pragma unroll
    for (int i = 0; i < 4; i++)
#pragma unroll
        for (int j = 0; j < 2; j++) acc[i][j] = (f32x4){0.f, 0.f, 0.f, 0.f};

    for (int kb_i = 0; kb_i < 8; ++kb_i) {
        const int k0 = kb_i * 128;
#pragma unroll
        for (int c = 0; c < 8; ++c) {
            int r0 = c * 16 + w * 4;
            int r = r0 + ri4;
            int sc = (ci16 ^ (r & 7)) << 3;
            gll16(A + (size_t)(row0 + r) * D_ + k0 + sc, &As[r0 * 128]);
        }
#pragma unroll
        for (int c = 0; c < 4; ++c) {
            int r0 = c * 16 + w * 4;
            int r = r0 + ri4;
            int sc = (ci16 ^ (r & 7)) << 3;
            gll16(W + (size_t)(col0 + r) * D_ + k0 + sc, &Bs[r0 * 128]);
        }
        __syncthreads();
#pragma unroll
        for (int ks = 0; ks < 4; ++ks) {
            bf16x8 af[4], bfr[2];
#pragma unroll
            for (int mt = 0; mt < 4; ++mt) {
                int r = wrow + mt * 16 + ln;
                af[mt] = *(bf16x8*)&As[r * 128 + (((ks * 4 + quad) ^ (r & 7)) << 3)];
            }
#pragma unroll
            for (int nt = 0; nt < 2; ++nt) {
                int r = wcol + nt * 16 + ln;
                bfr[nt] = *(bf16x8*)&Bs[r * 128 + (((ks * 4 + quad) ^ (r & 7)) << 3)];
            }
#pragma unroll
            for (int mt = 0; mt < 4; ++mt)
#pragma unroll
                for (int nt = 0; nt < 2; ++nt)
                    acc[mt][nt] = __builtin_amdgcn_mfma_f32_16x16x32_bf16(
                        af[mt], bfr[nt], acc[mt][nt], 0, 0, 0);
        }
        __syncthreads();
    }
#pragma unroll
    for (int mt = 0; mt < 4; ++mt) {
#pragma unroll
        for (int nt = 0; nt < 2; ++nt) {
            int n = col0 + wcol + nt * 16 + ln;
            float bv = bias[n];
#pragma unroll
            for (int reg = 0; reg < 4; ++reg) {
                int m = row0 + wrow + mt * 16 + quad * 4 + reg;
                out[(size_t)m * D_ + n] = acc[mt][nt][reg] + bv;
            }
        }
    }
}

// ---------------------------------------------------------------------------
extern "C" void kernel_launch(void* const* d_in, const int* in_sizes, int n_in,
                              void* d_out, int out_size, void* d_ws, size_t ws_size,
                              hipStream_t stream)
{
    const float* iQ  = (const float*)d_in[0];
    const float* Wa  = (const float*)d_in[1];
    const float* ba  = (const float*)d_in[2];
    const float* rel = (const float*)d_in[3];
    const float* snb = (const float*)d_in[4];
    const float* Wo  = (const float*)d_in[5];
    const float* bo  = (const float*)d_in[6];
    float* outp = (float*)d_out;

    const size_t NQ = (size_t)B_ * S_ * D_;
    const size_t NWA = (size_t)3 * D_ * D_;
    const size_t NWO = (size_t)D_ * D_;
    const size_t PLANE = (size_t)B_ * H_ * S_ * AD_;

    u16* iQbf = (u16*)d_ws;          // reused as ctx after qkv_gemm
    u16* Wabf = iQbf + NQ;
    u16* Wobf = Wabf + NWA;
    u16* qbuf = Wobf + NWO;
    u16* kbuf = qbuf + PLANE;
    u16* vbuf = kbuf + PLANE;
    u16* ctx  = iQbf;

    conv_bf16<<<4096, 256, 0, stream>>>(iQ, Wa, Wo, iQbf, Wabf, Wobf,
                                        (int)NQ, (int)NWA);
    qkv_gemm<<<dim3(24, 32), 256, 0, stream>>>(iQbf, Wabf, ba, qbuf, kbuf, vbuf);
    attn_kernel<<<dim3(512), 256, 0, stream>>>(qbuf, kbuf, vbuf, rel, snb, ctx);
    out_gemm<<<dim3(16, 32), 256, 0, stream>>>(ctx, Wobf, bo, outp);
}

// Round 15
// 166.021 us; speedup vs baseline: 1.0412x; 1.0412x over previous
//
#include <hip/hip_runtime.h>
#include <hip/hip_bf16.h>
#include <stdint.h>

typedef unsigned short u16;
typedef unsigned int   u32;
typedef __attribute__((ext_vector_type(8))) __bf16 bf16x8;
typedef __attribute__((ext_vector_type(8))) _Float16 f16x8;
typedef __attribute__((ext_vector_type(2))) _Float16 f16x2;
typedef __attribute__((ext_vector_type(4))) float  f32x4;
typedef __attribute__((ext_vector_type(2))) u32    u32x2;
typedef __attribute__((ext_vector_type(4))) u32    u32x4;

#define B_  4
#define S_  1024
#define D_  1024
#define H_  16
#define AD_ 64

#if defined(__has_builtin)
#if __has_builtin(__builtin_amdgcn_cvt_pk_bf16_f32)
#define HAVE_CVT_PK 1
#endif
#if __has_builtin(__builtin_amdgcn_global_load_lds)
#define HAVE_GLL 1
#endif
#endif

#ifdef HAVE_CVT_PK
typedef __attribute__((ext_vector_type(2))) __bf16 bf16x2;
__device__ __forceinline__ u32 pack2(float a, float b) {
    bf16x2 r = __builtin_amdgcn_cvt_pk_bf16_f32(a, b);
    return __builtin_bit_cast(u32, r);
}
__device__ __forceinline__ u16 f2bf(float f) { return (u16)pack2(f, f); }
#else
__device__ __forceinline__ u16 f2bf(float f) {
    u32 u = __float_as_uint(f);
    u32 r = u + 0x7fffu + ((u >> 16) & 1u);   // RNE
    return (u16)(r >> 16);
}
__device__ __forceinline__ u32 pack2(float a, float b) {
    return (u32)f2bf(a) | ((u32)f2bf(b) << 16);
}
#endif

// pack two f32 into f16x2 (RTZ) as u32
__device__ __forceinline__ u32 pkf16(float a, float b) {
    return __builtin_bit_cast(u32, __builtin_amdgcn_cvt_pkrtz(a, b));
}
// t = relu(x)^2 for a pair, in packed f16 (cvt + pk_max + pk_mul)
__device__ __forceinline__ u32 relu2_f16(float a, float b) {
    f16x2 h = __builtin_bit_cast(f16x2, __builtin_amdgcn_cvt_pkrtz(a, b));
    f16x2 z = {(_Float16)0.f, (_Float16)0.f};
    h = __builtin_elementwise_max(h, z);
    h = h * h;
    return __builtin_bit_cast(u32, h);
}

// Async global->LDS, 16B/lane; dest = base + lane*16 (wave-uniform base).
// Source-side XOR swizzle preserves the LDS XOR fragment layout.
typedef __attribute__((address_space(1))) const u32 gas_u32;
typedef __attribute__((address_space(3))) u32 las_u32;
__device__ __forceinline__ void gll16(const void* g, void* l) {
#ifdef HAVE_GLL
    __builtin_amdgcn_global_load_lds((gas_u32*)g, (las_u32*)l, 16, 0, 0);
#else
    int lane = threadIdx.x & 63;
    *(uint4*)((u16*)l + lane * 8) = *(const uint4*)g;
#endif
}

// ---------------------------------------------------------------------------
// Kernel 0: fp32 -> bf16 pre-conversion of iQ, Wa, Wo (memory-bound).
// Halving GEMM staging bytes was the single biggest win (R1->R2: +75us).
// ---------------------------------------------------------------------------
__global__ __launch_bounds__(256) void conv_bf16(
    const float* __restrict__ a, const float* __restrict__ b,
    const float* __restrict__ c,
    u16* __restrict__ ao, u16* __restrict__ bo, u16* __restrict__ co,
    int na, int nb)
{
    int gid = blockIdx.x * 256 + threadIdx.x;
    int base = gid * 8;
    const float* src; u16* dst; int off;
    if (base < na)           { src = a; dst = ao; off = base; }
    else if (base < na + nb) { src = b; dst = bo; off = base - na; }
    else                     { src = c; dst = co; off = base - na - nb; }
    float4 v0 = *(const float4*)(src + off);
    float4 v1 = *(const float4*)(src + off + 4);
    u32 pk[4] = {pack2(v0.x, v0.y), pack2(v0.z, v0.w),
                 pack2(v1.x, v1.y), pack2(v1.z, v1.w)};
    *(uint4*)(dst + off) = *(uint4*)pk;
}

// ---------------------------------------------------------------------------
// Kernel 1: QKV = iQ @ Wa^T + ba  (M=4096, N=3072, K=1024), bf16 inputs,
// gll16 async staging (source-side XOR swizzle). __launch_bounds__(256,3)
// caps VGPR so VGPR+AGPR fits 3 waves/SIMD (R9-measured win, 49 -> <45us).
// q (x0.125) bf16 [B,H,S,64], k bf16 [B,H,S,64], v f16 transposed [B,H,64,S].
// ---------------------------------------------------------------------------
__global__ __launch_bounds__(256, 3) void qkv_gemm(
    const u16* __restrict__ A, const u16* __restrict__ W,
    const float* __restrict__ bias,
    u16* __restrict__ qb, u16* __restrict__ kb, u16* __restrict__ vb)
{
    __shared__ u16 As[128 * 64];
    __shared__ u16 Bs[128 * 64];

    const int tid  = threadIdx.x;
    const int lane = tid & 63, w = tid >> 6;
    const int quad = lane >> 4, ln = lane & 15;
    const int wrow = (w >> 1) * 64, wcol = (w & 1) * 64;
    const int row0 = blockIdx.y * 128, col0 = blockIdx.x * 128;

    const int ri = lane >> 3, ci = lane & 7;
    const int scol = (ci ^ ri) << 3;

    f32x4 acc[4][4];
#pragma unroll
    for (int i = 0; i < 4; i++)
#pragma unroll
        for (int j = 0; j < 4; j++) acc[i][j] = (f32x4){0.f, 0.f, 0.f, 0.f};

    for (int kb_i = 0; kb_i < 16; ++kb_i) {
        const int k0 = kb_i * 64;
#pragma unroll
        for (int c = 0; c < 4; ++c) {
            int r0 = c * 32 + w * 8;
            int gr = r0 + ri;
            gll16(A + (size_t)(row0 + gr) * D_ + k0 + scol, &As[r0 * 64]);
            gll16(W + (size_t)(col0 + gr) * D_ + k0 + scol, &Bs[r0 * 64]);
        }
        __syncthreads();
#pragma unroll
        for (int ks = 0; ks < 2; ++ks) {
            bf16x8 af[4], bfr[4];
#pragma unroll
            for (int mt = 0; mt < 4; ++mt) {
                int r = wrow + mt * 16 + ln;
                af[mt] = *(bf16x8*)&As[r * 64 + (((ks * 4 + quad) ^ (r & 7)) << 3)];
            }
#pragma unroll
            for (int nt = 0; nt < 4; ++nt) {
                int r = wcol + nt * 16 + ln;
                bfr[nt] = *(bf16x8*)&Bs[r * 64 + (((ks * 4 + quad) ^ (r & 7)) << 3)];
            }
#pragma unroll
            for (int mt = 0; mt < 4; ++mt)
#pragma unroll
                for (int nt = 0; nt < 4; ++nt)
                    acc[mt][nt] = __builtin_amdgcn_mfma_f32_16x16x32_bf16(
                        af[mt], bfr[nt], acc[mt][nt], 0, 0, 0);
        }
        __syncthreads();
    }

    const int which = col0 >> 10;
#pragma unroll
    for (int mt = 0; mt < 4; ++mt) {
#pragma unroll
        for (int nt = 0; nt < 4; ++nt) {
            int n = col0 + wcol + nt * 16 + ln;
            float bv = bias[n];
            int h = (n >> 6) & 15, d = n & 63;
            if (which == 2) {
                int m0 = row0 + wrow + mt * 16 + quad * 4;
                int b = m0 >> 10, s0 = m0 & 1023;
                u32x2 pk;
                pk.x = pkf16(acc[mt][nt][0] + bv, acc[mt][nt][1] + bv);
                pk.y = pkf16(acc[mt][nt][2] + bv, acc[mt][nt][3] + bv);
                *(u32x2*)&vb[((size_t)((b * 16 + h) * 64 + d)) * 1024 + s0] = pk;
            } else {
#pragma unroll
                for (int reg = 0; reg < 4; ++reg) {
                    int m = row0 + wrow + mt * 16 + quad * 4 + reg;
                    int b = m >> 10, s = m & 1023;
                    float v = acc[mt][nt][reg] + bv;
                    if (which == 0)
                        qb[((size_t)((b * 16 + h) * 1024 + s)) * 64 + d] = f2bf(v * 0.125f);
                    else
                        kb[((size_t)((b * 16 + h) * 1024 + s)) * 64 + d] = f2bf(v);
                }
            }
        }
    }
}

// ---------------------------------------------------------------------------
// Kernel 2: fused attention — measured-best config (R11/R13, 171.6us total):
// 128-row Q-tile (prologue amortization beats occupancy — R10), double-
// buffered K/V via gll16 (dbuf@2blk == sbuf@3blk, R14), S^T formulation
// (lane's i fixed), far-field rel bias folded into MFMA C-init, t=relu(s)^2
// in packed f16, PV + row-sum(L) via f16 MFMA (ones B-fragment, C-layout
// matches output write), single division at the end (SparseNormer needs no
// online rescaling).
// ---------------------------------------------------------------------------
__global__ __launch_bounds__(256) void attn_kernel(
    const u16* __restrict__ qb, const u16* __restrict__ kb,
    const u16* __restrict__ vb, const float* __restrict__ rel,
    const float* __restrict__ snb_p, u16* __restrict__ ctx)
{
    __shared__ u16 q_s[128 * 64];
    __shared__ u16 k_s[2][64 * 64];
    __shared__ u16 v_s[2][64 * 64];
    __shared__ float qr[33 * 128];

    u16* t_s   = q_s;
    u16* rel_s = v_s[1];

    const int tid  = threadIdx.x;
    const int lane = tid & 63, w = tid >> 6;
    const int quad = lane >> 4, ln = lane & 15;
    const int bh = blockIdx.x >> 3, qt = blockIdx.x & 7;
    const int i0 = qt * 128;
    const float snb = snb_p[0];

    const u16* qplane = qb + ((size_t)bh * 1024 + i0) * 64;
    const u16* kplane = kb + (size_t)bh * 1024 * 64;
    const u16* vplane = vb + (size_t)bh * 64 * 1024;

    const int ri = lane >> 3, ci = lane & 7;
    const int scol = (ci ^ ri) << 3;

    const u32x4 ones_u = {0x3C003C00u, 0x3C003C00u, 0x3C003C00u, 0x3C003C00u};
    const f16x8 ones = __builtin_bit_cast(f16x8, ones_u);

#pragma unroll
    for (int c = 0; c < 4; ++c) {
        int r0 = w * 32 + c * 8;
        gll16(qplane + (size_t)(r0 + ri) * 64 + scol, &q_s[r0 * 64]);
    }
    for (int idx = tid; idx < 384; idx += 256) {
        int p = idx >> 3, c = idx & 7;
        u32 pk[4];
        if (p < 33) {
            const float* sp = rel + p * 64 + c * 8;
            float4 r0 = *(const float4*)sp;
            float4 r1 = *(const float4*)(sp + 4);
            pk[0] = pack2(r0.x, r0.y); pk[1] = pack2(r0.z, r0.w);
            pk[2] = pack2(r1.x, r1.y); pk[3] = pack2(r1.z, r1.w);
        } else { pk[0] = pk[1] = pk[2] = pk[3] = 0; }
        *(uint4*)&rel_s[p * 64 + ((c ^ (p & 7)) << 3)] = *(uint4*)pk;
    }
    __syncthreads();

    bf16x8 bq[2][2];   // [sub][ks]
#pragma unroll
    for (int sub = 0; sub < 2; ++sub) {
        int rq = w * 32 + sub * 16 + ln;
#pragma unroll
        for (int ks = 0; ks < 2; ++ks)
            bq[sub][ks] = *(bf16x8*)&q_s[rq * 64 + (((ks * 4 + quad) ^ (rq & 7)) << 3)];
    }

    // qr[p][i] = q[i]·rel[p] + snb  via MFMA
#pragma unroll
    for (int sub = 0; sub < 2; ++sub) {
        f32x4 qacc[3];
#pragma unroll
        for (int nt = 0; nt < 3; ++nt) qacc[nt] = (f32x4){0.f, 0.f, 0.f, 0.f};
#pragma unroll
        for (int ks = 0; ks < 2; ++ks) {
#pragma unroll
            for (int nt = 0; nt < 3; ++nt) {
                int rp = nt * 16 + ln;
                bf16x8 bp = *(bf16x8*)&rel_s[rp * 64 + (((ks * 4 + quad) ^ (rp & 7)) << 3)];
                qacc[nt] = __builtin_amdgcn_mfma_f32_16x16x32_bf16(bq[sub][ks], bp, qacc[nt], 0, 0, 0);
            }
        }
#pragma unroll
        for (int nt = 0; nt < 3; ++nt) {
            int p = nt * 16 + ln;
            if (p < 33) {
#pragma unroll
                for (int reg = 0; reg < 4; ++reg)
                    qr[p * 128 + w * 32 + sub * 16 + quad * 4 + reg] = qacc[nt][reg] + snb;
            }
        }
    }

#pragma unroll
    for (int c = 0; c < 2; ++c) {
        int r0 = w * 16 + c * 8;
        gll16(kplane + (size_t)(r0 + ri) * 64 + scol, &k_s[0][r0 * 64]);
        gll16(vplane + (size_t)(r0 + ri) * 1024 + scol, &v_s[0][r0 * 64]);
    }
    __syncthreads();

    float cL[2], cR[2];
#pragma unroll
    for (int sub = 0; sub < 2; ++sub) {
        int il = w * 32 + sub * 16 + ln;
        cL[sub] = qr[il];
        cR[sub] = qr[32 * 128 + il];
    }

    f32x4 o_acc[2][4], lacc[2];
#pragma unroll
    for (int sub = 0; sub < 2; ++sub) {
        lacc[sub] = (f32x4){0.f, 0.f, 0.f, 0.f};
#pragma unroll
        for (int nt = 0; nt < 4; ++nt) o_acc[sub][nt] = (f32x4){0.f, 0.f, 0.f, 0.f};
    }

    for (int jt = 0; jt < 16; ++jt) {
        const int cur = jt & 1;
        const int j0 = jt * 64;
        if (jt < 15) {
            const int nxt = 1 - cur;
#pragma unroll
            for (int c = 0; c < 2; ++c) {
                int r0 = w * 16 + c * 8;
                gll16(kplane + (size_t)(j0 + 64 + r0 + ri) * 64 + scol, &k_s[nxt][r0 * 64]);
                gll16(vplane + (size_t)(r0 + ri) * 1024 + (j0 + 64) + scol, &v_s[nxt][r0 * 64]);
            }
        }

        f32x4 sacc[2][4];
        bool faru[2][4];
#pragma unroll
        for (int sub = 0; sub < 2; ++sub) {
            const int ib = i0 + w * 32 + sub * 16;
#pragma unroll
            for (int mj = 0; mj < 4; ++mj) {
                const int diff = (j0 + mj * 16) - ib;
                faru[sub][mj] = (diff >= 32 || diff <= -32);
                float ci = faru[sub][mj] ? ((diff < 0) ? cL[sub] : cR[sub]) : 0.f;
                sacc[sub][mj] = (f32x4){ci, ci, ci, ci};
            }
        }
#pragma unroll
        for (int ks = 0; ks < 2; ++ks) {
#pragma unroll
            for (int mj = 0; mj < 4; ++mj) {
                int rk = mj * 16 + ln;
                bf16x8 ak = *(bf16x8*)&k_s[cur][rk * 64 + (((ks * 4 + quad) ^ (rk & 7)) << 3)];
                sacc[0][mj] = __builtin_amdgcn_mfma_f32_16x16x32_bf16(ak, bq[0][ks], sacc[0][mj], 0, 0, 0);
                sacc[1][mj] = __builtin_amdgcn_mfma_f32_16x16x32_bf16(ak, bq[1][ks], sacc[1][mj], 0, 0, 0);
            }
        }

#pragma unroll
        for (int sub = 0; sub < 2; ++sub) {
            const int ib = i0 + w * 32 + sub * 16;
            const int row = w * 32 + sub * 16 + ln;
#pragma unroll
            for (int mj = 0; mj < 4; ++mj) {
                u32x2 pk;
                if (faru[sub][mj]) {
                    pk.x = relu2_f16(sacc[sub][mj][0], sacc[sub][mj][1]);
                    pk.y = relu2_f16(sacc[sub][mj][2], sacc[sub][mj][3]);
                } else {
                    const int jg0 = j0 + mj * 16;
                    float sv[4];
#pragma unroll
                    for (int reg = 0; reg < 4; ++reg) {
                        int dlt = jg0 + quad * 4 + reg - (ib + ln);
                        int p = min(max(dlt, -16), 16) + 16;
                        sv[reg] = sacc[sub][mj][reg] + qr[p * 128 + row];
                    }
                    pk.x = relu2_f16(sv[0], sv[1]);
                    pk.y = relu2_f16(sv[2], sv[3]);
                }
                int chunk = ((2 * mj + (quad >> 1)) ^ (row & 7));
                *(u32x2*)&t_s[row * 64 + (chunk << 3) + (quad & 1) * 4] = pk;
            }
        }

#pragma unroll
        for (int ks = 0; ks < 2; ++ks) {
            f16x8 at[2];
#pragma unroll
            for (int sub = 0; sub < 2; ++sub) {
                int rt = w * 32 + sub * 16 + ln;
                at[sub] = *(f16x8*)&t_s[rt * 64 + (((ks * 4 + quad) ^ (rt & 7)) << 3)];
            }
            lacc[0] = __builtin_amdgcn_mfma_f32_16x16x32_f16(at[0], ones, lacc[0], 0, 0, 0);
            lacc[1] = __builtin_amdgcn_mfma_f32_16x16x32_f16(at[1], ones, lacc[1], 0, 0, 0);
#pragma unroll
            for (int nt = 0; nt < 4; ++nt) {
                int rv = nt * 16 + ln;
                f16x8 bv = *(f16x8*)&v_s[cur][rv * 64 + (((ks * 4 + quad) ^ (rv & 7)) << 3)];
                o_acc[0][nt] = __builtin_amdgcn_mfma_f32_16x16x32_f16(at[0], bv, o_acc[0][nt], 0, 0, 0);
                o_acc[1][nt] = __builtin_amdgcn_mfma_f32_16x16x32_f16(at[1], bv, o_acc[1][nt], 0, 0, 0);
            }
        }
        __syncthreads();
    }

    const int b = bh >> 4, h = bh & 15;
#pragma unroll
    for (int sub = 0; sub < 2; ++sub) {
#pragma unroll
        for (int reg = 0; reg < 4; ++reg) {
            int ig = i0 + w * 32 + sub * 16 + quad * 4 + reg;
            float li = 1.f / (lacc[sub][reg] + 1e-8f);
#pragma unroll
            for (int nt = 0; nt < 4; ++nt) {
                int dg = nt * 16 + ln;
                ctx[((size_t)(b * 1024 + ig)) * 1024 + h * 64 + dg] =
                    f2bf(o_acc[sub][nt][reg] * li);
            }
        }
    }
}

// ---------------------------------------------------------------------------
// Kernel 3: out = ctx @ Wo^T + bo  (M=4096, N=1024, K=1024), bf16 in, f32 out.
// 128x64 tiles, BK=128, 512 blocks (grid-limited at 2/CU).
// ---------------------------------------------------------------------------
__global__ __launch_bounds__(256) void out_gemm(
    const u16* __restrict__ A, const u16* __restrict__ W,
    const float* __restrict__ bias, float* __restrict__ out)
{
    __shared__ u16 As[128 * 128];   // 32KB
    __shared__ u16 Bs[64 * 128];    // 16KB

    const int tid  = threadIdx.x;
    const int lane = tid & 63, w = tid >> 6;
    const int quad = lane >> 4, ln = lane & 15;
    const int wrow = (w >> 1) * 64, wcol = (w & 1) * 32;
    const int row0 = blockIdx.y * 128, col0 = blockIdx.x * 64;

    const int ri4  = lane >> 4;
    const int ci16 = lane & 15;

    f32x4 acc[4][2];
#pragma unroll
    for (int i = 0; i < 4; i++)
#pragma unroll
        for (int j = 0; j < 2; j++) acc[i][j] = (f32x4){0.f, 0.f, 0.f, 0.f};

    for (int kb_i = 0; kb_i < 8; ++kb_i) {
        const int k0 = kb_i * 128;
#pragma unroll
        for (int c = 0; c < 8; ++c) {
            int r0 = c * 16 + w * 4;
            int r = r0 + ri4;
            int sc = (ci16 ^ (r & 7)) << 3;
            gll16(A + (size_t)(row0 + r) * D_ + k0 + sc, &As[r0 * 128]);
        }
#pragma unroll
        for (int c = 0; c < 4; ++c) {
            int r0 = c * 16 + w * 4;
            int r = r0 + ri4;
            int sc = (ci16 ^ (r & 7)) << 3;
            gll16(W + (size_t)(col0 + r) * D_ + k0 + sc, &Bs[r0 * 128]);
        }
        __syncthreads();
#pragma unroll
        for (int ks = 0; ks < 4; ++ks) {
            bf16x8 af[4], bfr[2];
#pragma unroll
            for (int mt = 0; mt < 4; ++mt) {
                int r = wrow + mt * 16 + ln;
                af[mt] = *(bf16x8*)&As[r * 128 + (((ks * 4 + quad) ^ (r & 7)) << 3)];
            }
#pragma unroll
            for (int nt = 0; nt < 2; ++nt) {
                int r = wcol + nt * 16 + ln;
                bfr[nt] = *(bf16x8*)&Bs[r * 128 + (((ks * 4 + quad) ^ (r & 7)) << 3)];
            }
#pragma unroll
            for (int mt = 0; mt < 4; ++mt)
#pragma unroll
                for (int nt = 0; nt < 2; ++nt)
                    acc[mt][nt] = __builtin_amdgcn_mfma_f32_16x16x32_bf16(
                        af[mt], bfr[nt], acc[mt][nt], 0, 0, 0);
        }
        __syncthreads();
    }
#pragma unroll
    for (int mt = 0; mt < 4; ++mt) {
#pragma unroll
        for (int nt = 0; nt < 2; ++nt) {
            int n = col0 + wcol + nt * 16 + ln;
            float bv = bias[n];
#pragma unroll
            for (int reg = 0; reg < 4; ++reg) {
                int m = row0 + wrow + mt * 16 + quad * 4 + reg;
                out[(size_t)m * D_ + n] = acc[mt][nt][reg] + bv;
            }
        }
    }
}

// ---------------------------------------------------------------------------
extern "C" void kernel_launch(void* const* d_in, const int* in_sizes, int n_in,
                              void* d_out, int out_size, void* d_ws, size_t ws_size,
                              hipStream_t stream)
{
    const float* iQ  = (const float*)d_in[0];
    const float* Wa  = (const float*)d_in[1];
    const float* ba  = (const float*)d_in[2];
    const float* rel = (const float*)d_in[3];
    const float* snb = (const float*)d_in[4];
    const float* Wo  = (const float*)d_in[5];
    const float* bo  = (const float*)d_in[6];
    float* outp = (float*)d_out;

    const size_t NQ = (size_t)B_ * S_ * D_;
    const size_t NWA = (size_t)3 * D_ * D_;
    const size_t NWO = (size_t)D_ * D_;
    const size_t PLANE = (size_t)B_ * H_ * S_ * AD_;

    u16* iQbf = (u16*)d_ws;          // reused as ctx after qkv_gemm
    u16* Wabf = iQbf + NQ;
    u16* Wobf = Wabf + NWA;
    u16* qbuf = Wobf + NWO;
    u16* kbuf = qbuf + PLANE;
    u16* vbuf = kbuf + PLANE;
    u16* ctx  = iQbf;

    conv_bf16<<<4096, 256, 0, stream>>>(iQ, Wa, Wo, iQbf, Wabf, Wobf,
                                        (int)NQ, (int)NWA);
    qkv_gemm<<<dim3(24, 32), 256, 0, stream>>>(iQbf, Wabf, ba, qbuf, kbuf, vbuf);
    attn_kernel<<<dim3(512), 256, 0, stream>>>(qbuf, kbuf, vbuf, rel, snb, ctx);
    out_gemm<<<dim3(16, 32), 256, 0, stream>>>(ctx, Wobf, bo, outp);
}